// Round 10
// baseline (73.030 us; speedup 1.0000x reference)
//
#include <hip/hip_runtime.h>

// Head: fused QKV projection + causal attention, MI355X (gfx950)
// B=512, T=256, C=384, D=64. fp32 in/out, bf16 MFMA compute.
// One block = one batch. 1024 thr = 16 waves, 144 KB LDS, 1 block/CU.
// Phase 1 is ZERO-BARRIER: full W staged to LDS once in FRAGMENT-MAJOR
// layout (144 frags x 1KB; frag read = ds_read_b128 of contiguous 1KB ->
// conflict-free; staging write = linear id*16 -> conflict-free). Wave w
// streams its own 16 x-rows global->reg (depth-2 pipeline). 3 barriers total.
// Q never touches LDS: accumulator fragments feed phase-2 QK^T directly
// via the pi k-permutation; K is stored pi-permuted in LDS to match.

typedef short s16x8 __attribute__((ext_vector_type(8)));
typedef float f32x4 __attribute__((ext_vector_type(4)));
typedef float f32x2 __attribute__((ext_vector_type(2)));
typedef unsigned int u32;
typedef unsigned int u32x4 __attribute__((ext_vector_type(4)));
typedef unsigned short u16;
typedef unsigned short u16x4 __attribute__((ext_vector_type(4)));
typedef __bf16 bf16x2 __attribute__((ext_vector_type(2)));

__device__ __forceinline__ u32 cvt2(float x, float y) {
  f32x2 v = {x, y};
  bf16x2 b = __builtin_convertvector(v, bf16x2);
  return __builtin_bit_cast(u32, b);
}
__device__ __forceinline__ u16 f2bf(float f) {
  __bf16 b = (__bf16)f;
  return __builtin_bit_cast(u16, b);
}
__device__ __forceinline__ s16x8 pack8(float4 a, float4 b) {
  u32x4 p = {cvt2(a.x, a.y), cvt2(a.z, a.w), cvt2(b.x, b.y), cvt2(b.z, b.w)};
  return __builtin_bit_cast(s16x8, p);
}
__device__ __forceinline__ s16x8 mk_qf(f32x4 a, f32x4 b) {
  u32x4 p = {cvt2(a[0], a[1]), cvt2(a[2], a[3]), cvt2(b[0], b[1]), cvt2(b[2], b[3])};
  return __builtin_bit_cast(s16x8, p);
}

#define MFMA16 __builtin_amdgcn_mfma_f32_16x16x32_bf16

// LDS: phase 1: W fragment-major, frag(t,nt) at (t*12+nt)*1024 + lane*16.
// phase 2 overlay (W retired): K[256][128B] @0 | Vt[64][512B] @32768 |
//                              P[16 waves][2KB] @65536
#define VTOF 32768
#define POFF 65536

__global__ __launch_bounds__(1024) void head_kernel(
    const float* __restrict__ x,
    const float* __restrict__ WQ, const float* __restrict__ WK,
    const float* __restrict__ WV, float* __restrict__ out)
{
  __shared__ char smem[147456];
  const int tid = threadIdx.x;
  const int l  = tid & 63;
  const int w  = tid >> 6;
  const int g  = l >> 4, li = l & 15;
  const long bbase = (long)blockIdx.x * 256;

  const int myrow = 16 * w + li;                 // this lane's x-row (in batch)
  const float* px = x + (bbase + myrow) * 384 + g * 8;

  // ---- issue first two x k-chunks (in flight across W staging) ----
  float4 a0 = *reinterpret_cast<const float4*>(px);
  float4 a1 = *reinterpret_cast<const float4*>(px + 4);
  float4 b0 = *reinterpret_cast<const float4*>(px + 32);
  float4 b1 = *reinterpret_cast<const float4*>(px + 36);

  // ---- stage full W once, fragment-major: id -> dest byte id*16 ----
  // id decomposition: li'=id&15, g'=(id>>4)&3, ft=id>>6; t=ft/12, nt=ft%12.
  // source: W row n=nt*16+li', k-offset t*32+g'*8 (8 f32 -> 8 bf16).
#pragma unroll 3
  for (int i = 0; i < 9; ++i) {
    int id = tid + 1024 * i;                     // 0..9215
    int li_ = id & 15, g_ = (id >> 4) & 3, ft = id >> 6;
    int t_ = ft / 12, nt_ = ft - t_ * 12;
    int n = nt_ * 16 + li_;
    const float* wsrc = (n < 64) ? (WQ + n * 384)
                       : (n < 128) ? (WK + (n - 64) * 384)
                                   : (WV + (n - 128) * 384);
    float4 wa = *reinterpret_cast<const float4*>(wsrc + t_ * 32 + g_ * 8);
    float4 wb = *reinterpret_cast<const float4*>(wsrc + t_ * 32 + g_ * 8 + 4);
    *reinterpret_cast<s16x8*>(smem + id * 16) = pack8(wa, wb);
  }
  __syncthreads();                               // barrier #1

  f32x4 acc[12];
#pragma unroll
  for (int nt = 0; nt < 12; ++nt) acc[nt] = (f32x4){0.f, 0.f, 0.f, 0.f};

  // ---- phase 1: 12 k-tiles, ZERO barriers, depth-2 register pipeline ----
#pragma unroll 1
  for (int t = 0; t < 12; t += 2) {
    s16x8 xfA = pack8(a0, a1);
    if (t + 2 < 12) {
      a0 = *reinterpret_cast<const float4*>(px + (t + 2) * 32);
      a1 = *reinterpret_cast<const float4*>(px + (t + 2) * 32 + 4);
    }
    {
      const char* fb = smem + t * 12288 + l * 16;
#pragma unroll
      for (int nt = 0; nt < 12; ++nt) {
        s16x8 af = *reinterpret_cast<const s16x8*>(fb + nt * 1024);
        acc[nt] = MFMA16(af, xfA, acc[nt], 0, 0, 0);
      }
    }
    s16x8 xfB = pack8(b0, b1);
    if (t + 3 < 12) {
      b0 = *reinterpret_cast<const float4*>(px + (t + 3) * 32);
      b1 = *reinterpret_cast<const float4*>(px + (t + 3) * 32 + 4);
    }
    {
      const char* fb = smem + (t + 1) * 12288 + l * 16;
#pragma unroll
      for (int nt = 0; nt < 12; ++nt) {
        s16x8 af = *reinterpret_cast<const s16x8*>(fb + nt * 1024);
        acc[nt] = MFMA16(af, xfB, acc[nt], 0, 0, 0);
      }
    }
  }
  __syncthreads();                               // barrier #2: all W reads done

  // ---- epilogue: lane (g,li) holds D[n=16nt+4g+r][row=myrow] ----
  // Q (acc[0..3]) -> registers, pi-native: qf covers phys k 8g+j with
  // Q-dim 4g+(j&3)+16(j>>2) (+32 for qf1).
  s16x8 qf0 = mk_qf(acc[0], acc[1]);
  s16x8 qf1 = mk_qf(acc[2], acc[3]);
  // K (acc[4..7]) -> LDS pi-permuted: phys elem p holds K[pi(p)].
#pragma unroll
  for (int mm = 0; mm < 4; ++mm) {
    const int Eb = 32 * (mm >> 1) + 8 * g + 4 * (mm & 1);
    u16x4 pk;
    pk[0] = f2bf(acc[4 + mm][0]); pk[1] = f2bf(acc[4 + mm][1]);
    pk[2] = f2bf(acc[4 + mm][2]); pk[3] = f2bf(acc[4 + mm][3]);
    *reinterpret_cast<u16x4*>(smem + myrow * 128 +
        (((Eb >> 3) ^ (myrow & 7)) << 4) + (Eb & 7) * 2) = pk;
  }
  // V (acc[8..11]) -> transposed Vt[d][kv]
#pragma unroll
  for (int mm = 0; mm < 4; ++mm)
#pragma unroll
    for (int r = 0; r < 4; ++r) {
      const int d = mm * 16 + 4 * g + r;
      *reinterpret_cast<u16*>(smem + VTOF + d * 512 +
          ((myrow * 2) ^ ((d & 7) << 4))) = f2bf(acc[8 + mm][r]);
    }
  __syncthreads();                               // barrier #3: K/V ready

  // ---- phase 2: causal attention; wave w owns q-tile qt = w ----
  char* Pw = smem + POFF + w * 2048;
  const int qt = w;

  f32x4 o[4];
  float m[4], lsum[4];
#pragma unroll
  for (int r = 0; r < 4; ++r) { m[r] = -1e30f; lsum[r] = 0.f; }
#pragma unroll
  for (int nd = 0; nd < 4; ++nd) o[nd] = (f32x4){0.f, 0.f, 0.f, 0.f};

  const int nc = (qt >> 2) + 1;
#pragma unroll 1
  for (int c = 0; c < nc; ++c) {
    // ---- S = Q K^T (pi-consistent on both operands) ----
    f32x4 s[4];
#pragma unroll
    for (int nj = 0; nj < 4; ++nj) s[nj] = (f32x4){0.f, 0.f, 0.f, 0.f};
#pragma unroll
    for (int nj = 0; nj < 4; ++nj) {
      const int rb = c * 64 + nj * 16 + li;
      s16x8 kf0 = *reinterpret_cast<const s16x8*>(
          smem + rb * 128 + (((0 + g) ^ (rb & 7)) << 4));
      s16x8 kf1 = *reinterpret_cast<const s16x8*>(
          smem + rb * 128 + (((4 + g) ^ (rb & 7)) << 4));
      s[nj] = MFMA16(qf0, kf0, s[nj], 0, 0, 0);
      s[nj] = MFMA16(qf1, kf1, s[nj], 0, 0, 0);
    }
    const bool last = (c == nc - 1);
    // ---- scale + causal mask ----
#pragma unroll
    for (int nj = 0; nj < 4; ++nj)
#pragma unroll
      for (int r = 0; r < 4; ++r) {
        float v = s[nj][r] * 0.125f;
        if (last && (c * 64 + nj * 16 + li) > (qt * 16 + g * 4 + r)) v = -1e30f;
        s[nj][r] = v;
      }
    // ---- online max ----
    float alpha[4];
#pragma unroll
    for (int r = 0; r < 4; ++r) {
      float pm = fmaxf(fmaxf(s[0][r], s[1][r]), fmaxf(s[2][r], s[3][r]));
      pm = fmaxf(pm, __shfl_xor(pm, 1));
      pm = fmaxf(pm, __shfl_xor(pm, 2));
      pm = fmaxf(pm, __shfl_xor(pm, 4));
      pm = fmaxf(pm, __shfl_xor(pm, 8));
      float mn = fmaxf(m[r], pm);
      alpha[r] = __expf(m[r] - mn);
      m[r] = mn;
    }
    // ---- P = exp(S-m) -> per-wave LDS (swizzled) ----
    float psum[4] = {0.f, 0.f, 0.f, 0.f};
#pragma unroll
    for (int nj = 0; nj < 4; ++nj)
#pragma unroll
      for (int r = 0; r < 4; ++r) {
        float p = __expf(s[nj][r] - m[r]);
        psum[r] += p;
        int rowp = g * 4 + r;
        *reinterpret_cast<u16*>(
            Pw + rowp * 128 + ((nj * 32 + li * 2) ^ ((rowp & 7) << 4))) = f2bf(p);
      }
#pragma unroll
    for (int r = 0; r < 4; ++r) {
      float ps = psum[r];
      ps += __shfl_xor(ps, 1);
      ps += __shfl_xor(ps, 2);
      ps += __shfl_xor(ps, 4);
      ps += __shfl_xor(ps, 8);
      lsum[r] = lsum[r] * alpha[r] + ps;
    }
#pragma unroll
    for (int nd = 0; nd < 4; ++nd)
#pragma unroll
      for (int r = 0; r < 4; ++r) o[nd][r] *= alpha[r];

    __asm__ volatile("s_waitcnt lgkmcnt(0)" ::: "memory");
    // ---- O += P V ----
    s16x8 pa[2];
#pragma unroll
    for (int kk = 0; kk < 2; ++kk)
      pa[kk] = *reinterpret_cast<const s16x8*>(
          Pw + li * 128 + (((kk * 4 + g) ^ (li & 7)) << 4));
#pragma unroll
    for (int nd = 0; nd < 4; ++nd) {
#pragma unroll
      for (int kk = 0; kk < 2; ++kk) {
        const int d = nd * 16 + li;
        s16x8 vf = *reinterpret_cast<const s16x8*>(
            smem + VTOF + d * 512 + ((c * 128 + kk * 64 + g * 16) ^ ((d & 7) << 4)));
        o[nd] = MFMA16(pa[kk], vf, o[nd], 0, 0, 0);
      }
    }
  }
  // ---- output ----
#pragma unroll
  for (int r = 0; r < 4; ++r) lsum[r] = 1.f / lsum[r];
#pragma unroll
  for (int nd = 0; nd < 4; ++nd)
#pragma unroll
    for (int r = 0; r < 4; ++r)
      out[(bbase + qt * 16 + g * 4 + r) * 64 + nd * 16 + li] = o[nd][r] * lsum[r];
}

extern "C" void kernel_launch(void* const* d_in, const int* in_sizes, int n_in,
                              void* d_out, int out_size, void* d_ws, size_t ws_size,
                              hipStream_t stream) {
  const float* x  = (const float*)d_in[0];
  const float* WQ = (const float*)d_in[1];
  const float* WK = (const float*)d_in[2];
  const float* WV = (const float*)d_in[3];
  float* out = (float*)d_out;

  head_kernel<<<dim3(512), dim3(1024), 0, stream>>>(x, WQ, WK, WV, out);
}